// Round 5
// baseline (100.161 us; speedup 1.0000x reference)
//
#include <hip/hip_runtime.h>
#include <hip/hip_bf16.h>

#define EMBED 256
#define LL 6   // layers

typedef __attribute__((ext_vector_type(8))) __bf16 bf16x8;
typedef __attribute__((ext_vector_type(4))) float f32x4;

// sigmoid(x) > 0.05  <=>  x > -ln(19)
#define SEL_THR (-2.9444389791664403f)

// ================= K12: block 0 = calib+select+bvec; blocks 1..32 = W prep ==
// block = 1024 threads.
__global__ __launch_bounds__(1024) void k12(
        const float* __restrict__ cls, int n,             // last-layer inf classes
        const float* __restrict__ rt,
        const float* __restrict__ W0, const float* __restrict__ W1,
        const float* __restrict__ b0, const float* __restrict__ b1,
        float* __restrict__ calib,
        int* __restrict__ bbox, int* __restrict__ cnt,
        __bf16* __restrict__ Wt0, __bf16* __restrict__ Wt1,
        float* __restrict__ bvec0, float* __restrict__ bvec1) {
    int tid = threadIdx.x;

    if (blockIdx.x != 0) {
        // ---------- W transpose -> bf16, 64x64 tile ----------
        int idx0 = blockIdx.x - 1;
        int which = idx0 >> 4;
        int t = idx0 & 15;
        int k0 = (t >> 2) * 64, c0 = (t & 3) * 64;
        const float* W = which ? W1 : W0;
        __bf16* Wt     = which ? Wt1 : Wt0;
        __shared__ float T[64][65];
#pragma unroll
        for (int i = 0; i < 4; ++i) {
            int idx = i * 1024 + tid;
            int kk = idx >> 6, cc = idx & 63;
            T[kk][cc] = W[(size_t)(k0 + kk) * EMBED + c0 + cc];
        }
        __syncthreads();
#pragma unroll
        for (int i = 0; i < 4; ++i) {
            int idx = i * 1024 + tid;
            int cc = idx >> 6, kk = idx & 63;
            Wt[(size_t)(c0 + cc) * EMBED + k0 + kk] = (__bf16)T[kk][cc];
        }
        return;
    }

    // ---------- block 0: calib (thread 0), select scan, bvec ----------
    __shared__ int warpCnt[16];
    __shared__ float s_calib[16];
    int wid = tid >> 6, lane = tid & 63;

    if (tid == 0) {
        double a[4][8];
        for (int i = 0; i < 4; ++i)
            for (int j = 0; j < 4; ++j) {
                a[i][j]     = (double)rt[j * 4 + i];
                a[i][4 + j] = (i == j) ? 1.0 : 0.0;
            }
        for (int c = 0; c < 4; ++c) {
            int p = c; double best = fabs(a[c][c]);
            for (int r = c + 1; r < 4; ++r) { double v = fabs(a[r][c]); if (v > best) { best = v; p = r; } }
            if (p != c) for (int j = 0; j < 8; ++j) { double t2 = a[c][j]; a[c][j] = a[p][j]; a[p][j] = t2; }
            double inv = 1.0 / a[c][c];
            for (int j = 0; j < 8; ++j) a[c][j] *= inv;
            for (int r = 0; r < 4; ++r) if (r != c) {
                double f = a[r][c];
                for (int j = 0; j < 8; ++j) a[r][j] -= f * a[c][j];
            }
        }
        for (int i = 0; i < 4; ++i)
            for (int j = 0; j < 4; ++j) {
                float v = (float)a[i][4 + j];
                calib[i * 4 + j] = v;
                s_calib[i * 4 + j] = v;
            }
    }

    // select: thread t owns contiguous [t*PT, t*PT+PT) (PT x4, <=64 elems)
    int PT = ((n + 1023) / 1024 + 3) & ~3;
    int PT4 = PT >> 2;
    int start = tid * PT;

    float4 v[16];
#pragma unroll
    for (int j4 = 0; j4 < 16; ++j4) {
        if (j4 < PT4) {
            int s = start + j4 * 4;
            if (s + 4 <= n) {
                v[j4] = *(const float4*)&cls[s];
            } else {
                float4 t2; t2.x = t2.y = t2.z = t2.w = -1e30f;
                if (s + 0 < n) t2.x = cls[s + 0];
                if (s + 1 < n) t2.y = cls[s + 1];
                if (s + 2 < n) t2.z = cls[s + 2];
                if (s + 3 < n) t2.w = cls[s + 3];
                v[j4] = t2;
            }
        }
    }
    int c = 0;
#pragma unroll
    for (int j4 = 0; j4 < 16; ++j4) {
        if (j4 < PT4) {
            c += (v[j4].x > SEL_THR) + (v[j4].y > SEL_THR) +
                 (v[j4].z > SEL_THR) + (v[j4].w > SEL_THR);
        }
    }
    int incl = c;
#pragma unroll
    for (int off = 1; off < 64; off <<= 1) {
        int u = __shfl_up(incl, off, 64);
        if (lane >= off) incl += u;
    }
    if (lane == 63) warpCnt[wid] = incl;
    __syncthreads();   // warpCnt + s_calib ready

    int base = 0;
    for (int w2 = 0; w2 < wid; ++w2) base += warpCnt[w2];
    int pos = base + incl - c;
#pragma unroll
    for (int j4 = 0; j4 < 16; ++j4) {
        if (j4 < PT4) {
            int s = start + j4 * 4;
            if (s + 0 < n && v[j4].x > SEL_THR) bbox[pos++] = (s + 0) / 3;
            if (s + 1 < n && v[j4].y > SEL_THR) bbox[pos++] = (s + 1) / 3;
            if (s + 2 < n && v[j4].z > SEL_THR) bbox[pos++] = (s + 2) / 3;
            if (s + 3 < n && v[j4].w > SEL_THR) bbox[pos++] = (s + 3) / 3;
        }
    }
    if (tid == 0) {
        int tot = 0;
        for (int w2 = 0; w2 < 16; ++w2) tot += warpCnt[w2];
        *cnt = tot;
    }

    // bvec: threads 0..511 (which = tid>>8, col = tid&255)
    if (tid < 512) {
        int which = tid >> 8;
        int j = tid & 255;
        const float* W = which ? W1 : W0;
        const float* b = which ? b1 : b0;
        float* o       = which ? bvec1 : bvec0;
        float s = b[j];
#pragma unroll
        for (int u = 0; u < 9; ++u) {
            float r = s_calib[(u / 3) * 4 + (u % 3)];
            s += r * W[(EMBED + u) * EMBED + j];
        }
        o[j] = s;
    }
}

// ================= K34: gemm + veh copies + inf gathers, one grid ===========
// jobs: 0=gemm(q0) 1=gemm(q1) 2=veh_q 3=veh_qp 4=veh_cls 5=veh_coord 6=veh_ref
//       7=inf_cls 8=inf_coord 9=inf_ref
struct Plan34 {
    const float* vsrc[5];   // cls, coord, q, qp, ref
    const float* isrc[3];   // inf_cls, inf_coord, inf_ref
    const float* q0; const float* q1;
    const __bf16* Wt0; const __bf16* Wt1;
    const float* bvec0; const float* bvec1;
    int start[11];
    int n4[5];              // float4 counts per copy job (cls,coord,q,qp,ref)
    int vdst[5];            // dst base per copy job
    int idst[3];            // dst base per gather job
    int perLay4[2];         // cls, coord
    int layStride[2];
    int gemmOff0, gemmOff1;
    int K, NI, NV, N;
};

__device__ __forceinline__ float inv_sig(float v) {
    v = fminf(fmaxf(v, 0.0f), 1.0f);
    float x1 = fmaxf(v, 1e-5f);
    float x2 = fmaxf(1.0f - v, 1e-5f);
    return logf(x1 / x2);
}

__device__ __forceinline__ bf16x8 cvt8(float4 f0, float4 f1) {
    bf16x8 r;
    r[0] = (__bf16)f0.x; r[1] = (__bf16)f0.y; r[2] = (__bf16)f0.z; r[3] = (__bf16)f0.w;
    r[4] = (__bf16)f1.x; r[5] = (__bf16)f1.y; r[6] = (__bf16)f1.z; r[7] = (__bf16)f1.w;
    return r;
}

__device__ void gemm_block(const float* __restrict__ q, const __bf16* __restrict__ Wt,
                           const float* __restrict__ bvec, const int* __restrict__ bbox,
                           float* __restrict__ out, int NI, int K, int out_off, int lb) {
    int tid  = threadIdx.x;
    int w    = tid >> 6;
    int lane = tid & 63;
    int lo16 = lane & 15;
    int kg   = lane >> 4;
    int r0 = lb * 64;

    const float* aptr[4];
#pragma unroll
    for (int t = 0; t < 4; ++t) {
        int row = r0 + 16 * t + lo16;
        int rc = min(row, K - 1);
        int box = bbox[rc]; box = max(0, min(box, NI - 1));
        aptr[t] = q + (size_t)box * EMBED + kg * 8;
    }
    const __bf16* bptr[4];
#pragma unroll
    for (int t = 0; t < 4; ++t) {
        int col = w * 64 + 16 * t + lo16;
        bptr[t] = Wt + (size_t)col * EMBED + kg * 8;
    }

    f32x4 acc[4][4];
#pragma unroll
    for (int ct = 0; ct < 4; ++ct) {
        float bv = bvec[w * 64 + 16 * ct + lo16];
#pragma unroll
        for (int rt = 0; rt < 4; ++rt) {
            acc[rt][ct][0] = bv; acc[rt][ct][1] = bv; acc[rt][ct][2] = bv; acc[rt][ct][3] = bv;
        }
    }
    for (int s = 0; s < 8; ++s) {
        bf16x8 a[4], b[4];
#pragma unroll
        for (int t = 0; t < 4; ++t) {
            float4 f0 = *(const float4*)(aptr[t] + s * 32);
            float4 f1 = *(const float4*)(aptr[t] + s * 32 + 4);
            a[t] = cvt8(f0, f1);
            b[t] = *(const bf16x8*)(bptr[t] + s * 32);
        }
#pragma unroll
        for (int rt = 0; rt < 4; ++rt)
#pragma unroll
            for (int ct = 0; ct < 4; ++ct)
                acc[rt][ct] = __builtin_amdgcn_mfma_f32_16x16x32_bf16(a[rt], b[ct], acc[rt][ct], 0, 0, 0);
    }
#pragma unroll
    for (int rt = 0; rt < 4; ++rt) {
#pragma unroll
        for (int reg = 0; reg < 4; ++reg) {
            int row = r0 + 16 * rt + kg * 4 + reg;
            if (row < K) {
#pragma unroll
                for (int ct = 0; ct < 4; ++ct) {
                    int col = w * 64 + 16 * ct + lo16;
                    out[out_off + (size_t)row * EMBED + col] = acc[rt][ct][reg];
                }
            }
        }
    }
}

__global__ __launch_bounds__(256) void k34(Plan34 P, const int* __restrict__ bbox,
                                           const float* __restrict__ calib,
                                           float* __restrict__ out) {
    int bx = blockIdx.x;
    int j = 0;
    while (bx >= P.start[j + 1]) ++j;
    int lb  = bx - P.start[j];
    int tid = threadIdx.x;

    if (j < 2) {   // ---- gemm ----
        if (j == 0) gemm_block(P.q0, P.Wt0, P.bvec0, bbox, out, P.NI, P.K, P.gemmOff0, lb);
        else        gemm_block(P.q1, P.Wt1, P.bvec1, bbox, out, P.NI, P.K, P.gemmOff1, lb);
        return;
    }

    if (j < 7) {   // ---- veh copies, 4 x float4/thread ----
        const int cmap[5] = {2, 3, 0, 1, 4};   // job order q,qp,cls,coord,ref
        int cj = cmap[j - 2];
#pragma unroll
        for (int it = 0; it < 4; ++it) {
            int i4 = lb * 1024 + it * 256 + tid;
            if (i4 < P.n4[cj]) {
                float4 v = *(const float4*)&P.vsrc[cj][(size_t)i4 * 4];
                size_t d;
                if (cj < 2) {
                    int l = i4 / P.perLay4[cj];
                    int r = i4 - l * P.perLay4[cj];
                    d = (size_t)P.vdst[cj] + (size_t)l * P.layStride[cj] + (size_t)r * 4;
                } else {
                    d = (size_t)P.vdst[cj] + (size_t)i4 * 4;
                }
                *(float4*)&out[d] = v;
            }
        }
        return;
    }

    int k = lb * 256 + tid;
    if (k >= P.K) return;
    int box = bbox[k]; box = max(0, min(box, P.NI - 1));

    if (j == 7) {                      // ---- inf classes gather ----
        const float* s0 = P.isrc[0];
#pragma unroll
        for (int l = 0; l < LL; ++l) {
            const float* s = s0 + ((size_t)l * P.NI + box) * 3;
            size_t d = (size_t)P.idst[0] + ((size_t)l * P.N + P.NV) * 3 + (size_t)k * 3;
            out[d + 0] = s[0]; out[d + 1] = s[1]; out[d + 2] = s[2];
        }
    } else if (j == 8) {               // ---- inf coords gather+transform ----
        float c00 = calib[0], c01 = calib[1], c03 = calib[3];
        float c10 = calib[4], c11 = calib[5], c13 = calib[7];
        float zx = calib[2] * -5.0f, zy = calib[6] * -5.0f;
#pragma unroll
        for (int l = 0; l < LL; ++l) {
            float4 s = *(const float4*)&P.isrc[1][((size_t)l * P.NI + box) * 4];
            float X = s.x * 102.4f;
            float Y = s.y * 102.4f - 51.2f;
            float tx = c00 * X + c01 * Y + zx + c03;
            float ty = c10 * X + c11 * Y + zy + c13;
            float4 v = make_float4((tx + 51.2f) * (1.0f / 102.4f),
                                   (ty + 51.2f) * (1.0f / 102.4f), s.z, s.w);
            *(float4*)&out[(size_t)P.idst[1] + ((size_t)l * P.N + P.NV + k) * 4] = v;
        }
    } else {                           // ---- inf reference ----
        float4 s = *(const float4*)&P.isrc[2][(size_t)box * 4];
        float sx = 1.0f / (1.0f + expf(-s.x));
        float sy = 1.0f / (1.0f + expf(-s.y));
        float X = sx * 102.4f;
        float Y = sy * 102.4f - 51.2f;
        float tx = calib[0] * X + calib[1] * Y + calib[2] * -1.0f + calib[3];
        float ty = calib[4] * X + calib[5] * Y + calib[6] * -1.0f + calib[7];
        float4 v = make_float4(inv_sig((tx + 51.2f) * (1.0f / 102.4f)),
                               inv_sig((ty + 51.2f) * (1.0f / 102.4f)), s.z, s.w);
        *(float4*)&out[(size_t)P.idst[2] + ((size_t)P.NV + k) * 4] = v;
    }
}

extern "C" void kernel_launch(void* const* d_in, const int* in_sizes, int n_in,
                              void* d_out, int out_size, void* d_ws, size_t ws_size,
                              hipStream_t stream) {
    const float* inf_cls   = (const float*)d_in[0];
    const float* inf_coord = (const float*)d_in[1];
    const float* inf_q     = (const float*)d_in[2];
    const float* inf_qp    = (const float*)d_in[3];
    const float* inf_ref   = (const float*)d_in[4];
    const float* veh_cls   = (const float*)d_in[5];
    const float* veh_coord = (const float*)d_in[6];
    const float* veh_q     = (const float*)d_in[7];
    const float* veh_qp    = (const float*)d_in[8];
    const float* veh_ref   = (const float*)d_in[9];
    const float* rt        = (const float*)d_in[10];
    const float* W0        = (const float*)d_in[11];
    const float* b0        = (const float*)d_in[12];
    const float* W1        = (const float*)d_in[13];
    const float* b1        = (const float*)d_in[14];
    float* out = (float*)d_out;

    int NI = in_sizes[0] / (LL * 3);
    int NV = in_sizes[5] / (LL * 3);
    int N  = out_size / 558;
    int K  = N - NV;

    int off_cls   = 0;
    int off_coord = LL * N * 3;
    int off_q     = off_coord + LL * N * 4;
    int off_qp    = off_q + N * EMBED;
    int off_ref   = off_qp + N * EMBED;

    char* ws = (char*)d_ws;
    float* calib = (float*)(ws);
    float* bvec0 = (float*)(ws + 128);
    float* bvec1 = (float*)(ws + 1152);
    int*   cnt   = (int*)(ws + 2176);
    int*   bbox  = (int*)(ws + 2304);
    __bf16* Wt0  = (__bf16*)(ws + 131072);
    __bf16* Wt1  = (__bf16*)(ws + 262144);

    // K12: 1 select/calib/bvec block + 32 W-prep tiles
    hipLaunchKernelGGL(k12, dim3(33), dim3(1024), 0, stream,
                       inf_cls + (size_t)(LL - 1) * NI * 3, NI * 3, rt,
                       W0, W1, b0, b1, calib, bbox, cnt, Wt0, Wt1, bvec0, bvec1);

    // K34: everything else in one grid
    {
        Plan34 P;
        P.vsrc[0] = veh_cls; P.vsrc[1] = veh_coord; P.vsrc[2] = veh_q;
        P.vsrc[3] = veh_qp;  P.vsrc[4] = veh_ref;
        P.isrc[0] = inf_cls; P.isrc[1] = inf_coord; P.isrc[2] = inf_ref;
        P.q0 = inf_q; P.q1 = inf_qp;
        P.Wt0 = Wt0; P.Wt1 = Wt1; P.bvec0 = bvec0; P.bvec1 = bvec1;
        P.n4[0] = LL * NV * 3 / 4;  P.n4[1] = LL * NV * 4 / 4;
        P.n4[2] = NV * EMBED / 4;   P.n4[3] = NV * EMBED / 4;  P.n4[4] = NV * 4 / 4;
        P.vdst[0] = off_cls; P.vdst[1] = off_coord; P.vdst[2] = off_q;
        P.vdst[3] = off_qp;  P.vdst[4] = off_ref;
        P.idst[0] = off_cls; P.idst[1] = off_coord; P.idst[2] = off_ref;
        P.perLay4[0] = NV * 3 / 4;  P.perLay4[1] = NV * 4 / 4;
        P.layStride[0] = N * 3;     P.layStride[1] = N * 4;
        P.gemmOff0 = off_q + NV * EMBED;
        P.gemmOff1 = off_qp + NV * EMBED;
        P.K = K; P.NI = NI; P.NV = NV; P.N = N;

        int nbG = (K > 0) ? (K + 63) / 64 : 0;
        int gblk = (K > 0) ? (K + 255) / 256 : 0;
        int nb[10];
        nb[0] = nbG; nb[1] = nbG;                                   // gemm
        nb[2] = (P.n4[2] + 1023) / 1024;                            // veh_q
        nb[3] = (P.n4[3] + 1023) / 1024;                            // veh_qp
        nb[4] = (P.n4[0] + 1023) / 1024;                            // veh_cls
        nb[5] = (P.n4[1] + 1023) / 1024;                            // veh_coord
        nb[6] = (P.n4[4] + 1023) / 1024;                            // veh_ref
        nb[7] = gblk; nb[8] = gblk; nb[9] = gblk;                   // inf gathers
        P.start[0] = 0;
        for (int j = 0; j < 10; ++j) P.start[j + 1] = P.start[j] + nb[j];
        if (P.start[10] > 0) {
            hipLaunchKernelGGL(k34, dim3(P.start[10]), dim3(256), 0, stream,
                               P, bbox, calib, out);
        }
    }
}

// Round 6
// 63.815 us; speedup vs baseline: 1.5696x; 1.5696x over previous
//
#include <hip/hip_runtime.h>
#include <hip/hip_bf16.h>

#define EMBED 256
#define LL 6   // layers

typedef __attribute__((ext_vector_type(8))) __bf16 bf16x8;
typedef __attribute__((ext_vector_type(4))) float f32x4;

// sigmoid(x) > 0.05  <=>  x > -ln(19)
#define SEL_THR (-2.9444389791664403f)

// ================= K12: block 0 = calib+select+bvec; blocks 1..32 = W prep ==
__global__ __launch_bounds__(1024) void k12(
        const float* __restrict__ cls, int n,             // last-layer inf classes
        const float* __restrict__ rt,
        const float* __restrict__ W0, const float* __restrict__ W1,
        const float* __restrict__ b0, const float* __restrict__ b1,
        float* __restrict__ calib,
        int* __restrict__ bbox, int* __restrict__ cnt,
        __bf16* __restrict__ Wt0, __bf16* __restrict__ Wt1,
        float* __restrict__ bvec0, float* __restrict__ bvec1) {
    int tid = threadIdx.x;

    if (blockIdx.x != 0) {
        // ---------- W transpose -> bf16, 64x64 tile ----------
        int idx0 = blockIdx.x - 1;
        int which = idx0 >> 4;
        int t = idx0 & 15;
        int k0 = (t >> 2) * 64, c0 = (t & 3) * 64;
        const float* W = which ? W1 : W0;
        __bf16* Wt     = which ? Wt1 : Wt0;
        __shared__ float T[64][65];
#pragma unroll
        for (int i = 0; i < 4; ++i) {
            int idx = i * 1024 + tid;
            int kk = idx >> 6, cc = idx & 63;
            T[kk][cc] = W[(size_t)(k0 + kk) * EMBED + c0 + cc];
        }
        __syncthreads();
#pragma unroll
        for (int i = 0; i < 4; ++i) {
            int idx = i * 1024 + tid;
            int cc = idx >> 6, kk = idx & 63;
            Wt[(size_t)(c0 + cc) * EMBED + k0 + kk] = (__bf16)T[kk][cc];
        }
        return;
    }

    // ---------- block 0: calib (thread 0), select scan, bvec ----------
    __shared__ int warpCnt[16];
    __shared__ float s_calib[16];
    int wid = tid >> 6, lane = tid & 63;

    if (tid == 0) {
        double a[4][8];
        for (int i = 0; i < 4; ++i)
            for (int j = 0; j < 4; ++j) {
                a[i][j]     = (double)rt[j * 4 + i];
                a[i][4 + j] = (i == j) ? 1.0 : 0.0;
            }
        for (int c = 0; c < 4; ++c) {
            int p = c; double best = fabs(a[c][c]);
            for (int r = c + 1; r < 4; ++r) { double v = fabs(a[r][c]); if (v > best) { best = v; p = r; } }
            if (p != c) for (int j = 0; j < 8; ++j) { double t2 = a[c][j]; a[c][j] = a[p][j]; a[p][j] = t2; }
            double inv = 1.0 / a[c][c];
            for (int j = 0; j < 8; ++j) a[c][j] *= inv;
            for (int r = 0; r < 4; ++r) if (r != c) {
                double f = a[r][c];
                for (int j = 0; j < 8; ++j) a[r][j] -= f * a[c][j];
            }
        }
        for (int i = 0; i < 4; ++i)
            for (int j = 0; j < 4; ++j) {
                float v = (float)a[i][4 + j];
                calib[i * 4 + j] = v;
                s_calib[i * 4 + j] = v;
            }
    }

    int PT = ((n + 1023) / 1024 + 3) & ~3;
    int PT4 = PT >> 2;
    int start = tid * PT;

    float4 v[16];
#pragma unroll
    for (int j4 = 0; j4 < 16; ++j4) {
        if (j4 < PT4) {
            int s = start + j4 * 4;
            if (s + 4 <= n) {
                v[j4] = *(const float4*)&cls[s];
            } else {
                float4 t2; t2.x = t2.y = t2.z = t2.w = -1e30f;
                if (s + 0 < n) t2.x = cls[s + 0];
                if (s + 1 < n) t2.y = cls[s + 1];
                if (s + 2 < n) t2.z = cls[s + 2];
                if (s + 3 < n) t2.w = cls[s + 3];
                v[j4] = t2;
            }
        }
    }
    int c = 0;
#pragma unroll
    for (int j4 = 0; j4 < 16; ++j4) {
        if (j4 < PT4) {
            c += (v[j4].x > SEL_THR) + (v[j4].y > SEL_THR) +
                 (v[j4].z > SEL_THR) + (v[j4].w > SEL_THR);
        }
    }
    int incl = c;
#pragma unroll
    for (int off = 1; off < 64; off <<= 1) {
        int u = __shfl_up(incl, off, 64);
        if (lane >= off) incl += u;
    }
    if (lane == 63) warpCnt[wid] = incl;
    __syncthreads();   // warpCnt + s_calib ready

    int base = 0;
    for (int w2 = 0; w2 < wid; ++w2) base += warpCnt[w2];
    int pos = base + incl - c;
#pragma unroll
    for (int j4 = 0; j4 < 16; ++j4) {
        if (j4 < PT4) {
            int s = start + j4 * 4;
            if (s + 0 < n && v[j4].x > SEL_THR) bbox[pos++] = (s + 0) / 3;
            if (s + 1 < n && v[j4].y > SEL_THR) bbox[pos++] = (s + 1) / 3;
            if (s + 2 < n && v[j4].z > SEL_THR) bbox[pos++] = (s + 2) / 3;
            if (s + 3 < n && v[j4].w > SEL_THR) bbox[pos++] = (s + 3) / 3;
        }
    }
    if (tid == 0) {
        int tot = 0;
        for (int w2 = 0; w2 < 16; ++w2) tot += warpCnt[w2];
        *cnt = tot;
    }

    if (tid < 512) {
        int which = tid >> 8;
        int j = tid & 255;
        const float* W = which ? W1 : W0;
        const float* b = which ? b1 : b0;
        float* o       = which ? bvec1 : bvec0;
        float s = b[j];
#pragma unroll
        for (int u = 0; u < 9; ++u) {
            float r = s_calib[(u / 3) * 4 + (u % 3)];
            s += r * W[(EMBED + u) * EMBED + j];
        }
        o[j] = s;
    }
}

// ================= K34: gemm + veh copies + inf gathers, one grid ===========
// jobs: 0=gemm(q0) 1=gemm(q1) 2=veh_q 3=veh_qp 4=veh_cls 5=veh_coord 6=veh_ref
//       7=inf_cls 8=inf_coord 9=inf_ref
struct Plan34 {
    const float* vsrc[5];   // cls, coord, q, qp, ref
    const float* isrc[3];   // inf_cls, inf_coord, inf_ref
    const float* q0; const float* q1;
    const __bf16* Wt0; const __bf16* Wt1;
    const float* bvec0; const float* bvec1;
    int start[11];
    int n4[5];              // float4 counts per copy job (cls,coord,q,qp,ref)
    int vdst[5];            // dst base per copy job
    int idst[3];            // dst base per gather job
    int perLay4[2];         // cls, coord
    int layStride[2];
    int gemmOff0, gemmOff1;
    int K, NI, NV, N;
};

__device__ __forceinline__ float inv_sig(float v) {
    v = fminf(fmaxf(v, 0.0f), 1.0f);
    float x1 = fmaxf(v, 1e-5f);
    float x2 = fmaxf(1.0f - v, 1e-5f);
    return logf(x1 / x2);
}

__device__ __forceinline__ bf16x8 cvt8(float4 f0, float4 f1) {
    bf16x8 r;
    r[0] = (__bf16)f0.x; r[1] = (__bf16)f0.y; r[2] = (__bf16)f0.z; r[3] = (__bf16)f0.w;
    r[4] = (__bf16)f1.x; r[5] = (__bf16)f1.y; r[6] = (__bf16)f1.z; r[7] = (__bf16)f1.w;
    return r;
}

__device__ void gemm_block(const float* __restrict__ q, const __bf16* __restrict__ Wt,
                           const float* __restrict__ bvec, const int* __restrict__ bbox,
                           float* __restrict__ out, int NI, int K, int out_off, int lb) {
    int tid  = threadIdx.x;
    int w    = tid >> 6;
    int lane = tid & 63;
    int lo16 = lane & 15;
    int kg   = lane >> 4;
    int r0 = lb * 64;

    const float* aptr[4];
#pragma unroll
    for (int t = 0; t < 4; ++t) {
        int row = r0 + 16 * t + lo16;
        int rc = min(row, K - 1);
        int box = bbox[rc]; box = max(0, min(box, NI - 1));
        aptr[t] = q + (size_t)box * EMBED + kg * 8;
    }
    const __bf16* bptr[4];
#pragma unroll
    for (int t = 0; t < 4; ++t) {
        int col = w * 64 + 16 * t + lo16;
        bptr[t] = Wt + (size_t)col * EMBED + kg * 8;
    }

    f32x4 acc[4][4];
#pragma unroll
    for (int ct = 0; ct < 4; ++ct) {
        float bv = bvec[w * 64 + 16 * ct + lo16];
#pragma unroll
        for (int rt = 0; rt < 4; ++rt) {
            acc[rt][ct][0] = bv; acc[rt][ct][1] = bv; acc[rt][ct][2] = bv; acc[rt][ct][3] = bv;
        }
    }
    for (int s = 0; s < 8; ++s) {
        bf16x8 a[4], b[4];
#pragma unroll
        for (int t = 0; t < 4; ++t) {
            float4 f0 = *(const float4*)(aptr[t] + s * 32);
            float4 f1 = *(const float4*)(aptr[t] + s * 32 + 4);
            a[t] = cvt8(f0, f1);
            b[t] = *(const bf16x8*)(bptr[t] + s * 32);
        }
#pragma unroll
        for (int rt = 0; rt < 4; ++rt)
#pragma unroll
            for (int ct = 0; ct < 4; ++ct)
                acc[rt][ct] = __builtin_amdgcn_mfma_f32_16x16x32_bf16(a[rt], b[ct], acc[rt][ct], 0, 0, 0);
    }
#pragma unroll
    for (int rt = 0; rt < 4; ++rt) {
#pragma unroll
        for (int reg = 0; reg < 4; ++reg) {
            int row = r0 + 16 * rt + kg * 4 + reg;
            if (row < K) {
#pragma unroll
                for (int ct = 0; ct < 4; ++ct) {
                    int col = w * 64 + 16 * ct + lo16;
                    out[out_off + (size_t)row * EMBED + col] = acc[rt][ct][reg];
                }
            }
        }
    }
}

// 4 blocks/CU minimum -> VGPR cap 128 (gemm path needed 92 standalone).
__global__ __launch_bounds__(256, 4) void k34(Plan34 P, const int* __restrict__ bbox,
                                              const float* __restrict__ calib,
                                              float* __restrict__ out) {
    int bx = blockIdx.x;
    int j = 0;
    while (bx >= P.start[j + 1]) ++j;
    int lb  = bx - P.start[j];
    int tid = threadIdx.x;

    if (j < 2) {   // ---- gemm (single call site to keep regalloc tight) ----
        const float* q    = j ? P.q1 : P.q0;
        const __bf16* Wt  = j ? P.Wt1 : P.Wt0;
        const float* bvec = j ? P.bvec1 : P.bvec0;
        int goff          = j ? P.gemmOff1 : P.gemmOff0;
        gemm_block(q, Wt, bvec, bbox, out, P.NI, P.K, goff, lb);
        return;
    }

    if (j < 7) {   // ---- veh copies, 4 x float4/thread ----
        const int cmap[5] = {2, 3, 0, 1, 4};   // job order q,qp,cls,coord,ref
        int cj = cmap[j - 2];
#pragma unroll
        for (int it = 0; it < 4; ++it) {
            int i4 = lb * 1024 + it * 256 + tid;
            if (i4 < P.n4[cj]) {
                float4 v = *(const float4*)&P.vsrc[cj][(size_t)i4 * 4];
                size_t d;
                if (cj < 2) {
                    int l = i4 / P.perLay4[cj];
                    int r = i4 - l * P.perLay4[cj];
                    d = (size_t)P.vdst[cj] + (size_t)l * P.layStride[cj] + (size_t)r * 4;
                } else {
                    d = (size_t)P.vdst[cj] + (size_t)i4 * 4;
                }
                *(float4*)&out[d] = v;
            }
        }
        return;
    }

    int k = lb * 256 + tid;
    if (k >= P.K) return;
    int box = bbox[k]; box = max(0, min(box, P.NI - 1));

    if (j == 7) {                      // ---- inf classes gather ----
        const float* s0 = P.isrc[0];
#pragma unroll
        for (int l = 0; l < LL; ++l) {
            const float* s = s0 + ((size_t)l * P.NI + box) * 3;
            size_t d = (size_t)P.idst[0] + ((size_t)l * P.N + P.NV) * 3 + (size_t)k * 3;
            out[d + 0] = s[0]; out[d + 1] = s[1]; out[d + 2] = s[2];
        }
    } else if (j == 8) {               // ---- inf coords gather+transform ----
        float c00 = calib[0], c01 = calib[1], c03 = calib[3];
        float c10 = calib[4], c11 = calib[5], c13 = calib[7];
        float zx = calib[2] * -5.0f, zy = calib[6] * -5.0f;
#pragma unroll
        for (int l = 0; l < LL; ++l) {
            float4 s = *(const float4*)&P.isrc[1][((size_t)l * P.NI + box) * 4];
            float X = s.x * 102.4f;
            float Y = s.y * 102.4f - 51.2f;
            float tx = c00 * X + c01 * Y + zx + c03;
            float ty = c10 * X + c11 * Y + zy + c13;
            float4 v = make_float4((tx + 51.2f) * (1.0f / 102.4f),
                                   (ty + 51.2f) * (1.0f / 102.4f), s.z, s.w);
            *(float4*)&out[(size_t)P.idst[1] + ((size_t)l * P.N + P.NV + k) * 4] = v;
        }
    } else {                           // ---- inf reference ----
        float4 s = *(const float4*)&P.isrc[2][(size_t)box * 4];
        float sx = 1.0f / (1.0f + expf(-s.x));
        float sy = 1.0f / (1.0f + expf(-s.y));
        float X = sx * 102.4f;
        float Y = sy * 102.4f - 51.2f;
        float tx = calib[0] * X + calib[1] * Y + calib[2] * -1.0f + calib[3];
        float ty = calib[4] * X + calib[5] * Y + calib[6] * -1.0f + calib[7];
        float4 v = make_float4(inv_sig((tx + 51.2f) * (1.0f / 102.4f)),
                               inv_sig((ty + 51.2f) * (1.0f / 102.4f)), s.z, s.w);
        *(float4*)&out[(size_t)P.idst[2] + ((size_t)P.NV + k) * 4] = v;
    }
}

extern "C" void kernel_launch(void* const* d_in, const int* in_sizes, int n_in,
                              void* d_out, int out_size, void* d_ws, size_t ws_size,
                              hipStream_t stream) {
    const float* inf_cls   = (const float*)d_in[0];
    const float* inf_coord = (const float*)d_in[1];
    const float* inf_q     = (const float*)d_in[2];
    const float* inf_qp    = (const float*)d_in[3];
    const float* inf_ref   = (const float*)d_in[4];
    const float* veh_cls   = (const float*)d_in[5];
    const float* veh_coord = (const float*)d_in[6];
    const float* veh_q     = (const float*)d_in[7];
    const float* veh_qp    = (const float*)d_in[8];
    const float* veh_ref   = (const float*)d_in[9];
    const float* rt        = (const float*)d_in[10];
    const float* W0        = (const float*)d_in[11];
    const float* b0        = (const float*)d_in[12];
    const float* W1        = (const float*)d_in[13];
    const float* b1        = (const float*)d_in[14];
    float* out = (float*)d_out;

    int NI = in_sizes[0] / (LL * 3);
    int NV = in_sizes[5] / (LL * 3);
    int N  = out_size / 558;
    int K  = N - NV;

    int off_cls   = 0;
    int off_coord = LL * N * 3;
    int off_q     = off_coord + LL * N * 4;
    int off_qp    = off_q + N * EMBED;
    int off_ref   = off_qp + N * EMBED;

    char* ws = (char*)d_ws;
    float* calib = (float*)(ws);
    float* bvec0 = (float*)(ws + 128);
    float* bvec1 = (float*)(ws + 1152);
    int*   cnt   = (int*)(ws + 2176);
    int*   bbox  = (int*)(ws + 2304);
    __bf16* Wt0  = (__bf16*)(ws + 131072);
    __bf16* Wt1  = (__bf16*)(ws + 262144);

    // K12: 1 select/calib/bvec block + 32 W-prep tiles
    hipLaunchKernelGGL(k12, dim3(33), dim3(1024), 0, stream,
                       inf_cls + (size_t)(LL - 1) * NI * 3, NI * 3, rt,
                       W0, W1, b0, b1, calib, bbox, cnt, Wt0, Wt1, bvec0, bvec1);

    // K34: everything else in one grid
    {
        Plan34 P;
        P.vsrc[0] = veh_cls; P.vsrc[1] = veh_coord; P.vsrc[2] = veh_q;
        P.vsrc[3] = veh_qp;  P.vsrc[4] = veh_ref;
        P.isrc[0] = inf_cls; P.isrc[1] = inf_coord; P.isrc[2] = inf_ref;
        P.q0 = inf_q; P.q1 = inf_qp;
        P.Wt0 = Wt0; P.Wt1 = Wt1; P.bvec0 = bvec0; P.bvec1 = bvec1;
        P.n4[0] = LL * NV * 3 / 4;  P.n4[1] = LL * NV * 4 / 4;
        P.n4[2] = NV * EMBED / 4;   P.n4[3] = NV * EMBED / 4;  P.n4[4] = NV * 4 / 4;
        P.vdst[0] = off_cls; P.vdst[1] = off_coord; P.vdst[2] = off_q;
        P.vdst[3] = off_qp;  P.vdst[4] = off_ref;
        P.idst[0] = off_cls; P.idst[1] = off_coord; P.idst[2] = off_ref;
        P.perLay4[0] = NV * 3 / 4;  P.perLay4[1] = NV * 4 / 4;
        P.layStride[0] = N * 3;     P.layStride[1] = N * 4;
        P.gemmOff0 = off_q + NV * EMBED;
        P.gemmOff1 = off_qp + NV * EMBED;
        P.K = K; P.NI = NI; P.NV = NV; P.N = N;

        int nbG = (K > 0) ? (K + 63) / 64 : 0;
        int gblk = (K > 0) ? (K + 255) / 256 : 0;
        int nb[10];
        nb[0] = nbG; nb[1] = nbG;                                   // gemm
        nb[2] = (P.n4[2] + 1023) / 1024;                            // veh_q
        nb[3] = (P.n4[3] + 1023) / 1024;                            // veh_qp
        nb[4] = (P.n4[0] + 1023) / 1024;                            // veh_cls
        nb[5] = (P.n4[1] + 1023) / 1024;                            // veh_coord
        nb[6] = (P.n4[4] + 1023) / 1024;                            // veh_ref
        nb[7] = gblk; nb[8] = gblk; nb[9] = gblk;                   // inf gathers
        P.start[0] = 0;
        for (int j = 0; j < 10; ++j) P.start[j + 1] = P.start[j] + nb[j];
        if (P.start[10] > 0) {
            hipLaunchKernelGGL(k34, dim3(P.start[10]), dim3(256), 0, stream,
                               P, bbox, calib, out);
        }
    }
}